// Round 1
// baseline (3015.169 us; speedup 1.0000x reference)
//
#include <hip/hip_runtime.h>
#include <math.h>

#define NXg 128
#define NYg 128
#define NTg 64
#define SEQ 128
#define DIM 64
#define NH 4
#define DHd 16
#define DFFd 128
#define NLAYER 2
#define EPSf 1e-5f

// dot of a 64-float weight row (global, uniform address -> scalar loads)
// with a 64-float register array.
__device__ __forceinline__ float dot64(const float* __restrict__ w, const float* h) {
  const float4* w4 = reinterpret_cast<const float4*>(w);
  float a0 = 0.f, a1 = 0.f, a2 = 0.f, a3 = 0.f;
#pragma unroll
  for (int i = 0; i < 16; ++i) {
    float4 wv = w4[i];
    a0 = fmaf(h[4 * i + 0], wv.x, a0);
    a1 = fmaf(h[4 * i + 1], wv.y, a1);
    a2 = fmaf(h[4 * i + 2], wv.z, a2);
    a3 = fmaf(h[4 * i + 3], wv.w, a3);
  }
  return (a0 + a1) + (a2 + a3);
}

__global__ __launch_bounds__(128)
void fieldformer_kernel(const int* __restrict__ q_lin_idx,
                        const int* __restrict__ offsets_ijk,
                        const float* __restrict__ coords,
                        const float* __restrict__ vals,
                        const float* __restrict__ log_gammas,
                        const float* __restrict__ proj_w,
                        const float* __restrict__ proj_b,
                        const float* __restrict__ qkv_w,
                        const float* __restrict__ qkv_b,
                        const float* __restrict__ out_w,
                        const float* __restrict__ out_b,
                        const float* __restrict__ ln1_s,
                        const float* __restrict__ ln1_b,
                        const float* __restrict__ ff1_w,
                        const float* __restrict__ ff1_b,
                        const float* __restrict__ ff2_w,
                        const float* __restrict__ ff2_b,
                        const float* __restrict__ ln2_s,
                        const float* __restrict__ ln2_b,
                        const float* __restrict__ head_ln_s,
                        const float* __restrict__ head_ln_b,
                        const float* __restrict__ head1_w,
                        const float* __restrict__ head1_b,
                        const float* __restrict__ head2_w,
                        const float* __restrict__ head2_b,
                        float* __restrict__ out)
{
  __shared__ float smem[16384];   // 64 KB: kT[64][128] + vT[64][128], reused at the end
  float* kT = smem;               // kT[c*SEQ + row] = K[row][c]
  float* vT = smem + DIM * SEQ;   // vT[c*SEQ + row] = V[row][c]

  const int b = blockIdx.x;
  const int r = threadIdx.x;      // one thread per sequence row (0..127)

  // ---------------- phase 0: build token, project to h-row (registers) ----
  const int q    = q_lin_idx[b];
  const int qi   = q / (NYg * NTg);
  const int qrem = q - qi * (NYg * NTg);
  const int qj   = qrem / NTg;
  const int qk   = qrem - qj * NTg;

  const int di = offsets_ijk[r * 3 + 0];
  const int dj = offsets_ijk[r * 3 + 1];
  const int dk = offsets_ijk[r * 3 + 2];
  const int I = (qi + di) % NXg;
  const int J = (qj + dj) % NYg;
  int T = qk + dk; T = T < 0 ? 0 : (T > NTg - 1 ? NTg - 1 : T);
  const int nb = I * (NYg * NTg) + J * NTg + T;

  const float qx = coords[q * 3 + 0], qy = coords[q * 3 + 1], qz = coords[q * 3 + 2];
  const float nx_ = coords[nb * 3 + 0], ny_ = coords[nb * 3 + 1], nz_ = coords[nb * 3 + 2];
  // periodic wrap: (a-b+L/2) mod L - L/2, with python-mod semantics (L=2)
  float ax = nx_ - qx + 1.0f; ax -= 2.0f * floorf(ax * 0.5f); ax -= 1.0f;
  float ay = ny_ - qy + 1.0f; ay -= 2.0f * floorf(ay * 0.5f); ay -= 1.0f;
  const float at = nz_ - qz;
  const float g0 = expf(log_gammas[0]);
  const float g1 = expf(log_gammas[1]);
  const float g2 = expf(log_gammas[2]);

  float tok[6];
  tok[0] = ax * g0; tok[1] = ay * g1; tok[2] = at * g2;
  tok[3] = vals[nb * 3 + 0]; tok[4] = vals[nb * 3 + 1]; tok[5] = vals[nb * 3 + 2];

  float h[DIM];   // row-stationary activation, lives in VGPRs for whole kernel
#pragma unroll
  for (int c = 0; c < DIM; ++c) {
    const float* w = proj_w + c * 6;
    float a = proj_b[c];
    a = fmaf(tok[0], w[0], a);
    a = fmaf(tok[1], w[1], a);
    a = fmaf(tok[2], w[2], a);
    a = fmaf(tok[3], w[3], a);
    a = fmaf(tok[4], w[4], a);
    a = fmaf(tok[5], w[5], a);
    h[c] = a;
  }

  // ---------------- transformer layers ------------------------------------
  for (int l = 0; l < NLAYER; ++l) {
    const float* wqkv = qkv_w + l * 3 * DIM * DIM;
    const float* bqkv = qkv_b + l * 3 * DIM;

    __syncthreads();  // previous consumers of smem are done
    // K,V rows -> LDS (transposed: writes conflict-free, reads broadcast)
    for (int c = 0; c < DIM; ++c) {
      float kc = dot64(wqkv + (DIM + c) * DIM, h) + bqkv[DIM + c];
      float vc = dot64(wqkv + (2 * DIM + c) * DIM, h) + bqkv[2 * DIM + c];
      kT[c * SEQ + r] = kc;
      vT[c * SEQ + r] = vc;
    }
    __syncthreads();

    // attention: per-thread online softmax over 128 keys, 4 keys per step.
    // out-proj folded per head into attacc; h stays pristine (q source).
    const float* ow = out_w + l * DIM * DIM;
    const float* ob = out_b + l * DIM;
    float attacc[DIM];
#pragma unroll
    for (int c = 0; c < DIM; ++c) attacc[c] = ob[c];

    for (int hd = 0; hd < NH; ++hd) {
      float qv[DHd];
#pragma unroll
      for (int t = 0; t < DHd; ++t)
        qv[t] = dot64(wqkv + (hd * DHd + t) * DIM, h) + bqkv[hd * DHd + t];

      float m = -INFINITY, lsum = 0.f;
      float o[DHd];
#pragma unroll
      for (int t = 0; t < DHd; ++t) o[t] = 0.f;

      for (int g = 0; g < SEQ / 4; ++g) {
        float s0 = 0.f, s1 = 0.f, s2 = 0.f, s3 = 0.f;
#pragma unroll
        for (int t = 0; t < DHd; ++t) {
          float4 kk = *reinterpret_cast<const float4*>(&kT[(hd * DHd + t) * SEQ + 4 * g]);
          s0 = fmaf(qv[t], kk.x, s0);
          s1 = fmaf(qv[t], kk.y, s1);
          s2 = fmaf(qv[t], kk.z, s2);
          s3 = fmaf(qv[t], kk.w, s3);
        }
        s0 *= 0.25f; s1 *= 0.25f; s2 *= 0.25f; s3 *= 0.25f;  // 1/sqrt(16)
        const float mn = fmaxf(m, fmaxf(fmaxf(s0, s1), fmaxf(s2, s3)));
        const float alpha = __expf(m - mn);                   // exp(-inf)=0 on first step
        const float p0 = __expf(s0 - mn), p1 = __expf(s1 - mn);
        const float p2 = __expf(s2 - mn), p3 = __expf(s3 - mn);
        lsum = lsum * alpha + ((p0 + p1) + (p2 + p3));
#pragma unroll
        for (int t = 0; t < DHd; ++t) {
          float4 vv = *reinterpret_cast<const float4*>(&vT[(hd * DHd + t) * SEQ + 4 * g]);
          float ot = o[t] * alpha;
          ot = fmaf(p0, vv.x, ot);
          ot = fmaf(p1, vv.y, ot);
          ot = fmaf(p2, vv.z, ot);
          ot = fmaf(p3, vv.w, ot);
          o[t] = ot;
        }
        m = mn;
      }
      const float inv_l = 1.0f / lsum;
      // fold this head's slice of the out-projection
#pragma unroll
      for (int c = 0; c < DIM; ++c) {
        const float4* ow4 = reinterpret_cast<const float4*>(ow + c * DIM + hd * DHd);
        float accu = 0.f;
#pragma unroll
        for (int t4 = 0; t4 < 4; ++t4) {
          float4 wv = ow4[t4];
          accu = fmaf(o[4 * t4 + 0], wv.x, accu);
          accu = fmaf(o[4 * t4 + 1], wv.y, accu);
          accu = fmaf(o[4 * t4 + 2], wv.z, accu);
          accu = fmaf(o[4 * t4 + 3], wv.w, accu);
        }
        attacc[c] = fmaf(accu, inv_l, attacc[c]);
      }
    }

    // residual + LN1 (all in registers)
    {
      const float* sv = ln1_s + l * DIM;
      const float* bv = ln1_b + l * DIM;
#pragma unroll
      for (int c = 0; c < DIM; ++c) h[c] += attacc[c];
      float mu = 0.f;
#pragma unroll
      for (int c = 0; c < DIM; ++c) mu += h[c];
      mu *= (1.0f / DIM);
      float var = 0.f;
#pragma unroll
      for (int c = 0; c < DIM; ++c) { float d = h[c] - mu; var = fmaf(d, d, var); }
      var *= (1.0f / DIM);
      const float rstd = rsqrtf(var + EPSf);
#pragma unroll
      for (int c = 0; c < DIM; ++c) h[c] = fmaf((h[c] - mu) * rstd, sv[c], bv[c]);
    }

    // FF: stream hidden units 4 at a time, 64-wide accumulator in registers
    {
      const float* w1 = ff1_w + l * DFFd * DIM;
      const float* b1 = ff1_b + l * DFFd;
      const float* w2 = ff2_w + l * DIM * DFFd;
      const float* b2 = ff2_b + l * DIM;
      float acc[DIM];
#pragma unroll
      for (int c = 0; c < DIM; ++c) acc[c] = b2[c];
      for (int g = 0; g < DFFd / 4; ++g) {
        const float a0 = fmaxf(dot64(w1 + (4 * g + 0) * DIM, h) + b1[4 * g + 0], 0.f);
        const float a1 = fmaxf(dot64(w1 + (4 * g + 1) * DIM, h) + b1[4 * g + 1], 0.f);
        const float a2 = fmaxf(dot64(w1 + (4 * g + 2) * DIM, h) + b1[4 * g + 2], 0.f);
        const float a3 = fmaxf(dot64(w1 + (4 * g + 3) * DIM, h) + b1[4 * g + 3], 0.f);
#pragma unroll
        for (int c = 0; c < DIM; ++c) {
          float4 wv = *reinterpret_cast<const float4*>(&w2[c * DFFd + 4 * g]);
          float a = acc[c];
          a = fmaf(a0, wv.x, a);
          a = fmaf(a1, wv.y, a);
          a = fmaf(a2, wv.z, a);
          a = fmaf(a3, wv.w, a);
          acc[c] = a;
        }
      }
      // residual + LN2
      const float* sv = ln2_s + l * DIM;
      const float* bv = ln2_b + l * DIM;
#pragma unroll
      for (int c = 0; c < DIM; ++c) h[c] += acc[c];
      float mu = 0.f;
#pragma unroll
      for (int c = 0; c < DIM; ++c) mu += h[c];
      mu *= (1.0f / DIM);
      float var = 0.f;
#pragma unroll
      for (int c = 0; c < DIM; ++c) { float d = h[c] - mu; var = fmaf(d, d, var); }
      var *= (1.0f / DIM);
      const float rstd = rsqrtf(var + EPSf);
#pragma unroll
      for (int c = 0; c < DIM; ++c) h[c] = fmaf((h[c] - mu) * rstd, sv[c], bv[c]);
    }
  }

  // ---------------- head: mean over S, LN, gelu-MLP -> 3 outputs ----------
  __syncthreads();                       // attention readers of smem are done
  float* hT  = smem;                     // [64][129] stride-129: conflict-free both ways
  float* g_s = smem + DIM * 129;         // 64 floats (offset 8256, 16B aligned)
  float* a_s = g_s + DIM;                // 64 floats
#pragma unroll
  for (int c = 0; c < DIM; ++c) hT[c * 129 + r] = h[c];
  __syncthreads();

  if (r < DIM) {
    float s = 0.f;
    for (int rr = 0; rr < SEQ; ++rr) s += hT[r * 129 + rr];
    const float hm = s * (1.0f / SEQ);
    // LayerNorm across the 64 lanes of wave 0
    float t = hm;
    t += __shfl_xor(t, 1, 64);
    t += __shfl_xor(t, 2, 64);
    t += __shfl_xor(t, 4, 64);
    t += __shfl_xor(t, 8, 64);
    t += __shfl_xor(t, 16, 64);
    t += __shfl_xor(t, 32, 64);
    const float mu = t * (1.0f / DIM);
    const float dv = hm - mu;
    float v2 = dv * dv;
    v2 += __shfl_xor(v2, 1, 64);
    v2 += __shfl_xor(v2, 2, 64);
    v2 += __shfl_xor(v2, 4, 64);
    v2 += __shfl_xor(v2, 8, 64);
    v2 += __shfl_xor(v2, 16, 64);
    v2 += __shfl_xor(v2, 32, 64);
    const float var = v2 * (1.0f / DIM);
    g_s[r] = fmaf(dv * rsqrtf(var + EPSf), head_ln_s[r], head_ln_b[r]);
  }
  __syncthreads();

  if (r < DIM) {
    const float4* w4 = reinterpret_cast<const float4*>(head1_w + r * DIM);
    const float4* gg4 = reinterpret_cast<const float4*>(g_s);
    float z = head1_b[r];
#pragma unroll
    for (int i = 0; i < 16; ++i) {
      float4 wv = w4[i];
      float4 gg = gg4[i];
      z = fmaf(gg.x, wv.x, z);
      z = fmaf(gg.y, wv.y, z);
      z = fmaf(gg.z, wv.z, z);
      z = fmaf(gg.w, wv.w, z);
    }
    // exact gelu
    a_s[r] = 0.5f * z * (1.0f + erff(z * 0.70710678118654752f));
  }
  __syncthreads();

  if (r < 3) {
    float z = head2_b[r];
    for (int d2 = 0; d2 < DIM; ++d2) z = fmaf(a_s[d2], head2_w[r * DIM + d2], z);
    out[b * 3 + r] = z;
  }
}

extern "C" void kernel_launch(void* const* d_in, const int* in_sizes, int n_in,
                              void* d_out, int out_size, void* d_ws, size_t ws_size,
                              hipStream_t stream) {
  (void)n_in; (void)d_ws; (void)ws_size; (void)out_size;
  const int B = in_sizes[0];
  fieldformer_kernel<<<dim3(B), dim3(128), 0, stream>>>(
      (const int*)d_in[0],    // q_lin_idx
      (const int*)d_in[1],    // offsets_ijk
      (const float*)d_in[2],  // coords
      (const float*)d_in[3],  // vals
      (const float*)d_in[4],  // log_gammas
      (const float*)d_in[5],  // proj_w
      (const float*)d_in[6],  // proj_b
      (const float*)d_in[7],  // qkv_w
      (const float*)d_in[8],  // qkv_b
      (const float*)d_in[9],  // out_w
      (const float*)d_in[10], // out_b
      (const float*)d_in[11], // ln1_s
      (const float*)d_in[12], // ln1_b
      (const float*)d_in[13], // ff1_w
      (const float*)d_in[14], // ff1_b
      (const float*)d_in[15], // ff2_w
      (const float*)d_in[16], // ff2_b
      (const float*)d_in[17], // ln2_s
      (const float*)d_in[18], // ln2_b
      (const float*)d_in[19], // head_ln_s
      (const float*)d_in[20], // head_ln_b
      (const float*)d_in[21], // head1_w
      (const float*)d_in[22], // head1_b
      (const float*)d_in[23], // head2_w
      (const float*)d_in[24], // head2_b
      (float*)d_out);
}

// Round 2
// 1766.298 us; speedup vs baseline: 1.7071x; 1.7071x over previous
//
#include <hip/hip_runtime.h>
#include <math.h>

#define NXg 128
#define NYg 128
#define NTg 64
#define SEQ 128
#define DIM 64
#define NH 4
#define DHd 16
#define DFFd 128
#define NLAYER 2
#define EPSf 1e-5f

// dot of a 64-float weight row (global, uniform address -> scalar loads)
// with a 64-float register array.
__device__ __forceinline__ float dot64(const float* __restrict__ w, const float* h) {
  const float4* w4 = reinterpret_cast<const float4*>(w);
  float a0 = 0.f, a1 = 0.f, a2 = 0.f, a3 = 0.f;
#pragma unroll
  for (int i = 0; i < 16; ++i) {
    float4 wv = w4[i];
    a0 = fmaf(h[4 * i + 0], wv.x, a0);
    a1 = fmaf(h[4 * i + 1], wv.y, a1);
    a2 = fmaf(h[4 * i + 2], wv.z, a2);
    a3 = fmaf(h[4 * i + 3], wv.w, a3);
  }
  return (a0 + a1) + (a2 + a3);
}

// LDS budget: 2*16*128*4 = 16 KB for per-head K/V + 1.0 KB scratch = 17.4 KB
// -> 9 blocks/CU by LDS; VGPR(~132, 3 waves/SIMD) caps at 6 blocks/CU
// = 12 waves/CU (~37% occupancy) vs 4 waves/CU for the 64 KB variant.
__global__ __launch_bounds__(128, 3)
void fieldformer_kernel(const int* __restrict__ q_lin_idx,
                        const int* __restrict__ offsets_ijk,
                        const float* __restrict__ coords,
                        const float* __restrict__ vals,
                        const float* __restrict__ log_gammas,
                        const float* __restrict__ proj_w,
                        const float* __restrict__ proj_b,
                        const float* __restrict__ qkv_w,
                        const float* __restrict__ qkv_b,
                        const float* __restrict__ out_w,
                        const float* __restrict__ out_b,
                        const float* __restrict__ ln1_s,
                        const float* __restrict__ ln1_b,
                        const float* __restrict__ ff1_w,
                        const float* __restrict__ ff1_b,
                        const float* __restrict__ ff2_w,
                        const float* __restrict__ ff2_b,
                        const float* __restrict__ ln2_s,
                        const float* __restrict__ ln2_b,
                        const float* __restrict__ head_ln_s,
                        const float* __restrict__ head_ln_b,
                        const float* __restrict__ head1_w,
                        const float* __restrict__ head1_b,
                        const float* __restrict__ head2_w,
                        const float* __restrict__ head2_b,
                        float* __restrict__ out)
{
  __shared__ float kT[DHd * SEQ];   // kT[t*SEQ + row] = K_head[row][t]   (8 KB)
  __shared__ float vT[DHd * SEQ];   // vT[t*SEQ + row] = V_head[row][t]   (8 KB)
  __shared__ float red[2 * DIM];    // per-wave column sums for the final mean
  __shared__ float gsc[DIM];
  __shared__ float asc[DIM];

  const int b = blockIdx.x;
  const int r = threadIdx.x;        // one thread per sequence row (0..127)
  const int lane = r & 63;
  const int wv_id = r >> 6;

  // ---------------- phase 0: build token, project to h-row (registers) ----
  const int q    = q_lin_idx[b];
  const int qi   = q / (NYg * NTg);
  const int qrem = q - qi * (NYg * NTg);
  const int qj   = qrem / NTg;
  const int qk   = qrem - qj * NTg;

  const int di = offsets_ijk[r * 3 + 0];
  const int dj = offsets_ijk[r * 3 + 1];
  const int dk = offsets_ijk[r * 3 + 2];
  const int I = (qi + di) % NXg;
  const int J = (qj + dj) % NYg;
  int T = qk + dk; T = T < 0 ? 0 : (T > NTg - 1 ? NTg - 1 : T);
  const int nb = I * (NYg * NTg) + J * NTg + T;

  const float qx = coords[q * 3 + 0], qy = coords[q * 3 + 1], qz = coords[q * 3 + 2];
  const float nx_ = coords[nb * 3 + 0], ny_ = coords[nb * 3 + 1], nz_ = coords[nb * 3 + 2];
  // periodic wrap: (a-b+L/2) mod L - L/2, python-mod semantics (L=2)
  float ax = nx_ - qx + 1.0f; ax -= 2.0f * floorf(ax * 0.5f); ax -= 1.0f;
  float ay = ny_ - qy + 1.0f; ay -= 2.0f * floorf(ay * 0.5f); ay -= 1.0f;
  const float at = nz_ - qz;
  const float g0 = expf(log_gammas[0]);
  const float g1 = expf(log_gammas[1]);
  const float g2 = expf(log_gammas[2]);

  float tok[6];
  tok[0] = ax * g0; tok[1] = ay * g1; tok[2] = at * g2;
  tok[3] = vals[nb * 3 + 0]; tok[4] = vals[nb * 3 + 1]; tok[5] = vals[nb * 3 + 2];

  float h[DIM];   // row-stationary activation, lives in VGPRs for whole kernel
#pragma unroll
  for (int c = 0; c < DIM; ++c) {
    const float* w = proj_w + c * 6;
    float a = proj_b[c];
    a = fmaf(tok[0], w[0], a);
    a = fmaf(tok[1], w[1], a);
    a = fmaf(tok[2], w[2], a);
    a = fmaf(tok[3], w[3], a);
    a = fmaf(tok[4], w[4], a);
    a = fmaf(tok[5], w[5], a);
    h[c] = a;
  }

  // ---------------- transformer layers ------------------------------------
  for (int l = 0; l < NLAYER; ++l) {
    const float* wqkv = qkv_w + l * 3 * DIM * DIM;
    const float* bqkv = qkv_b + l * 3 * DIM;
    const float* ow   = out_w + l * DIM * DIM;
    const float* ob   = out_b + l * DIM;

    float attacc[DIM];
#pragma unroll
    for (int c = 0; c < DIM; ++c) attacc[c] = ob[c];

    // per-head attention with per-head K/V staging (16 KB LDS, not 64 KB)
    for (int hd = 0; hd < NH; ++hd) {
      __syncthreads();  // previous consumers of kT/vT are done
      float qv[DHd];
#pragma unroll
      for (int t = 0; t < DHd; ++t) {
        qv[t]    = dot64(wqkv + (hd * DHd + t) * DIM, h)          + bqkv[hd * DHd + t];
        float kc = dot64(wqkv + (DIM + hd * DHd + t) * DIM, h)    + bqkv[DIM + hd * DHd + t];
        float vc = dot64(wqkv + (2 * DIM + hd * DHd + t) * DIM, h) + bqkv[2 * DIM + hd * DHd + t];
        kT[t * SEQ + r] = kc;   // lane index fastest -> conflict-free write
        vT[t * SEQ + r] = vc;
      }
      __syncthreads();

      // online softmax over 128 keys, 4 keys per step (reads are broadcasts)
      float m = -INFINITY, lsum = 0.f;
      float o[DHd];
#pragma unroll
      for (int t = 0; t < DHd; ++t) o[t] = 0.f;

      for (int g = 0; g < SEQ / 4; ++g) {
        float s0 = 0.f, s1 = 0.f, s2 = 0.f, s3 = 0.f;
#pragma unroll
        for (int t = 0; t < DHd; ++t) {
          float4 kk = *reinterpret_cast<const float4*>(&kT[t * SEQ + 4 * g]);
          s0 = fmaf(qv[t], kk.x, s0);
          s1 = fmaf(qv[t], kk.y, s1);
          s2 = fmaf(qv[t], kk.z, s2);
          s3 = fmaf(qv[t], kk.w, s3);
        }
        s0 *= 0.25f; s1 *= 0.25f; s2 *= 0.25f; s3 *= 0.25f;  // 1/sqrt(16)
        const float mn = fmaxf(m, fmaxf(fmaxf(s0, s1), fmaxf(s2, s3)));
        const float alpha = __expf(m - mn);                   // exp(-inf)=0 first step
        const float p0 = __expf(s0 - mn), p1 = __expf(s1 - mn);
        const float p2 = __expf(s2 - mn), p3 = __expf(s3 - mn);
        lsum = lsum * alpha + ((p0 + p1) + (p2 + p3));
#pragma unroll
        for (int t = 0; t < DHd; ++t) {
          float4 vvv = *reinterpret_cast<const float4*>(&vT[t * SEQ + 4 * g]);
          float ot = o[t] * alpha;
          ot = fmaf(p0, vvv.x, ot);
          ot = fmaf(p1, vvv.y, ot);
          ot = fmaf(p2, vvv.z, ot);
          ot = fmaf(p3, vvv.w, ot);
          o[t] = ot;
        }
        m = mn;
      }
      const float inv_l = 1.0f / lsum;
      // fold this head's slice of the out-projection
#pragma unroll
      for (int c = 0; c < DIM; ++c) {
        const float4* ow4 = reinterpret_cast<const float4*>(ow + c * DIM + hd * DHd);
        float accu = 0.f;
#pragma unroll
        for (int t4 = 0; t4 < 4; ++t4) {
          float4 wvv = ow4[t4];
          accu = fmaf(o[4 * t4 + 0], wvv.x, accu);
          accu = fmaf(o[4 * t4 + 1], wvv.y, accu);
          accu = fmaf(o[4 * t4 + 2], wvv.z, accu);
          accu = fmaf(o[4 * t4 + 3], wvv.w, accu);
        }
        attacc[c] = fmaf(accu, inv_l, attacc[c]);
      }
    }

    // residual + LN1 (all in registers)
    {
      const float* sv = ln1_s + l * DIM;
      const float* bv = ln1_b + l * DIM;
#pragma unroll
      for (int c = 0; c < DIM; ++c) h[c] += attacc[c];
      float mu = 0.f;
#pragma unroll
      for (int c = 0; c < DIM; ++c) mu += h[c];
      mu *= (1.0f / DIM);
      float var = 0.f;
#pragma unroll
      for (int c = 0; c < DIM; ++c) { float d = h[c] - mu; var = fmaf(d, d, var); }
      var *= (1.0f / DIM);
      const float rstd = rsqrtf(var + EPSf);
#pragma unroll
      for (int c = 0; c < DIM; ++c) h[c] = fmaf((h[c] - mu) * rstd, sv[c], bv[c]);
    }

    // FF: stream hidden units 4 at a time, 64-wide accumulator in registers
    {
      const float* w1 = ff1_w + l * DFFd * DIM;
      const float* b1 = ff1_b + l * DFFd;
      const float* w2 = ff2_w + l * DIM * DFFd;
      const float* b2 = ff2_b + l * DIM;
      float acc[DIM];
#pragma unroll
      for (int c = 0; c < DIM; ++c) acc[c] = b2[c];
      for (int g = 0; g < DFFd / 4; ++g) {
        const float a0 = fmaxf(dot64(w1 + (4 * g + 0) * DIM, h) + b1[4 * g + 0], 0.f);
        const float a1 = fmaxf(dot64(w1 + (4 * g + 1) * DIM, h) + b1[4 * g + 1], 0.f);
        const float a2 = fmaxf(dot64(w1 + (4 * g + 2) * DIM, h) + b1[4 * g + 2], 0.f);
        const float a3 = fmaxf(dot64(w1 + (4 * g + 3) * DIM, h) + b1[4 * g + 3], 0.f);
#pragma unroll
        for (int c = 0; c < DIM; ++c) {
          float4 wvv = *reinterpret_cast<const float4*>(&w2[c * DFFd + 4 * g]);
          float a = acc[c];
          a = fmaf(a0, wvv.x, a);
          a = fmaf(a1, wvv.y, a);
          a = fmaf(a2, wvv.z, a);
          a = fmaf(a3, wvv.w, a);
          acc[c] = a;
        }
      }
      // residual + LN2
      const float* sv = ln2_s + l * DIM;
      const float* bv = ln2_b + l * DIM;
#pragma unroll
      for (int c = 0; c < DIM; ++c) h[c] += acc[c];
      float mu = 0.f;
#pragma unroll
      for (int c = 0; c < DIM; ++c) mu += h[c];
      mu *= (1.0f / DIM);
      float var = 0.f;
#pragma unroll
      for (int c = 0; c < DIM; ++c) { float d = h[c] - mu; var = fmaf(d, d, var); }
      var *= (1.0f / DIM);
      const float rstd = rsqrtf(var + EPSf);
#pragma unroll
      for (int c = 0; c < DIM; ++c) h[c] = fmaf((h[c] - mu) * rstd, sv[c], bv[c]);
    }
  }

  // ---------------- head: mean over S (shuffle tree), LN, gelu-MLP --------
  // Column sums via per-wave butterfly: no 33 KB transpose buffer needed.
#pragma unroll
  for (int c = 0; c < DIM; ++c) {
    float v = h[c];
    v += __shfl_xor(v, 1, 64);
    v += __shfl_xor(v, 2, 64);
    v += __shfl_xor(v, 4, 64);
    v += __shfl_xor(v, 8, 64);
    v += __shfl_xor(v, 16, 64);
    v += __shfl_xor(v, 32, 64);
    if (lane == c) red[wv_id * DIM + c] = v;   // one store per thread, coalesced
  }
  __syncthreads();

  if (r < DIM) {
    const float hm = (red[r] + red[DIM + r]) * (1.0f / SEQ);
    // LayerNorm across the 64 lanes of wave 0
    float t = hm;
    t += __shfl_xor(t, 1, 64);
    t += __shfl_xor(t, 2, 64);
    t += __shfl_xor(t, 4, 64);
    t += __shfl_xor(t, 8, 64);
    t += __shfl_xor(t, 16, 64);
    t += __shfl_xor(t, 32, 64);
    const float mu = t * (1.0f / DIM);
    const float dv = hm - mu;
    float v2 = dv * dv;
    v2 += __shfl_xor(v2, 1, 64);
    v2 += __shfl_xor(v2, 2, 64);
    v2 += __shfl_xor(v2, 4, 64);
    v2 += __shfl_xor(v2, 8, 64);
    v2 += __shfl_xor(v2, 16, 64);
    v2 += __shfl_xor(v2, 32, 64);
    const float var = v2 * (1.0f / DIM);
    gsc[r] = fmaf(dv * rsqrtf(var + EPSf), head_ln_s[r], head_ln_b[r]);
  }
  __syncthreads();

  if (r < DIM) {
    const float4* w4  = reinterpret_cast<const float4*>(head1_w + r * DIM);
    const float4* gg4 = reinterpret_cast<const float4*>(gsc);
    float z = head1_b[r];
#pragma unroll
    for (int i = 0; i < 16; ++i) {
      float4 wvv = w4[i];
      float4 gg  = gg4[i];
      z = fmaf(gg.x, wvv.x, z);
      z = fmaf(gg.y, wvv.y, z);
      z = fmaf(gg.z, wvv.z, z);
      z = fmaf(gg.w, wvv.w, z);
    }
    // exact gelu
    asc[r] = 0.5f * z * (1.0f + erff(z * 0.70710678118654752f));
  }
  __syncthreads();

  if (r < 3) {
    float z = head2_b[r];
    for (int d2 = 0; d2 < DIM; ++d2) z = fmaf(asc[d2], head2_w[r * DIM + d2], z);
    out[b * 3 + r] = z;
  }
}

extern "C" void kernel_launch(void* const* d_in, const int* in_sizes, int n_in,
                              void* d_out, int out_size, void* d_ws, size_t ws_size,
                              hipStream_t stream) {
  (void)n_in; (void)d_ws; (void)ws_size; (void)out_size;
  const int B = in_sizes[0];
  fieldformer_kernel<<<dim3(B), dim3(128), 0, stream>>>(
      (const int*)d_in[0],    // q_lin_idx
      (const int*)d_in[1],    // offsets_ijk
      (const float*)d_in[2],  // coords
      (const float*)d_in[3],  // vals
      (const float*)d_in[4],  // log_gammas
      (const float*)d_in[5],  // proj_w
      (const float*)d_in[6],  // proj_b
      (const float*)d_in[7],  // qkv_w
      (const float*)d_in[8],  // qkv_b
      (const float*)d_in[9],  // out_w
      (const float*)d_in[10], // out_b
      (const float*)d_in[11], // ln1_s
      (const float*)d_in[12], // ln1_b
      (const float*)d_in[13], // ff1_w
      (const float*)d_in[14], // ff1_b
      (const float*)d_in[15], // ff2_w
      (const float*)d_in[16], // ff2_b
      (const float*)d_in[17], // ln2_s
      (const float*)d_in[18], // ln2_b
      (const float*)d_in[19], // head_ln_s
      (const float*)d_in[20], // head_ln_b
      (const float*)d_in[21], // head1_w
      (const float*)d_in[22], // head1_b
      (const float*)d_in[23], // head2_w
      (const float*)d_in[24], // head2_b
      (float*)d_out);
}

// Round 3
// 415.537 us; speedup vs baseline: 7.2561x; 4.2506x over previous
//
#include <hip/hip_runtime.h>
#include <math.h>

#define NXg 128
#define NYg 128
#define NTg 64
#define SEQ 128
#define DIM 64
#define NH 4
#define DHd 16
#define DFFd 128
#define NLAYER 2
#define EPSf 1e-5f

typedef _Float16 f16x8 __attribute__((ext_vector_type(8)));
typedef float f32x4 __attribute__((ext_vector_type(4)));

#define MFMA16(a, b, c) __builtin_amdgcn_mfma_f32_16x16x32_f16(a, b, c, 0, 0, 0)

__device__ __forceinline__ f16x8 zero8() {
  f16x8 z;
#pragma unroll
  for (int i = 0; i < 8; ++i) z[i] = (_Float16)0.0f;
  return z;
}
__device__ __forceinline__ f16x8 ld8(const _Float16* p) { return *(const f16x8*)p; }

// ---------------------------------------------------------------------------
// Prep: convert weight matrices to f16 into workspace.
// ws layout (halves): [0)      qkv  L*192*64 = 24576
//                     [24576)  out  L*64*64  =  8192
//                     [32768)  ff1  L*128*64 = 16384
//                     [49152)  ff2  L*64*128 = 16384   total 65536 halves
// ---------------------------------------------------------------------------
__global__ void prep_weights(const float* __restrict__ qkv_w,
                             const float* __restrict__ out_w,
                             const float* __restrict__ ff1_w,
                             const float* __restrict__ ff2_w,
                             _Float16* __restrict__ wsH) {
  int i = blockIdx.x * 256 + threadIdx.x;
  if (i < 24576) wsH[i] = (_Float16)qkv_w[i];
  else if (i < 32768) wsH[i] = (_Float16)out_w[i - 24576];
  else if (i < 49152) wsH[i] = (_Float16)ff1_w[i - 32768];
  else if (i < 65536) wsH[i] = (_Float16)ff2_w[i - 49152];
}

// residual + LayerNorm epilogue on C-layout f32 accumulators (rows own-wave),
// result written as f16 into sX. acc[mi][nt] covers cols nt*16+l15, rows
// (wv*2+mi)*16 + quad*4 + jr.
__device__ __forceinline__ void res_ln_store(f32x4 acc[2][4],
                                             const float* __restrict__ bias,
                                             const float* __restrict__ lns,
                                             const float* __restrict__ lnb,
                                             _Float16* sX,
                                             int wv, int quad, int l15) {
  float sv[4], bv[4], bb[4];
#pragma unroll
  for (int nt = 0; nt < 4; ++nt) {
    bb[nt] = bias[nt * 16 + l15];
    sv[nt] = lns[nt * 16 + l15];
    bv[nt] = lnb[nt * 16 + l15];
  }
#pragma unroll
  for (int mi = 0; mi < 2; ++mi) {
    float v[4][4];
#pragma unroll
    for (int nt = 0; nt < 4; ++nt)
#pragma unroll
      for (int jr = 0; jr < 4; ++jr) {
        int row = (wv * 2 + mi) * 16 + quad * 4 + jr;
        v[nt][jr] = acc[mi][nt][jr] + bb[nt] + (float)sX[row * 72 + nt * 16 + l15];
      }
#pragma unroll
    for (int jr = 0; jr < 4; ++jr) {
      float su = (v[0][jr] + v[1][jr]) + (v[2][jr] + v[3][jr]);
      su += __shfl_xor(su, 1, 64);
      su += __shfl_xor(su, 2, 64);
      su += __shfl_xor(su, 4, 64);
      su += __shfl_xor(su, 8, 64);
      const float mu = su * (1.0f / 64.0f);
      float q0 = 0.f;
#pragma unroll
      for (int nt = 0; nt < 4; ++nt) { float d = v[nt][jr] - mu; q0 = fmaf(d, d, q0); }
      q0 += __shfl_xor(q0, 1, 64);
      q0 += __shfl_xor(q0, 2, 64);
      q0 += __shfl_xor(q0, 4, 64);
      q0 += __shfl_xor(q0, 8, 64);
      const float rstd = rsqrtf(q0 * (1.0f / 64.0f) + EPSf);
#pragma unroll
      for (int nt = 0; nt < 4; ++nt) {
        int row = (wv * 2 + mi) * 16 + quad * 4 + jr;
        float o = fmaf((v[nt][jr] - mu) * rstd, sv[nt], bv[nt]);
        sX[row * 72 + nt * 16 + l15] = (_Float16)o;
      }
    }
  }
}

// ---------------------------------------------------------------------------
// Fused FieldFormer block: one workgroup (256 thr = 4 waves) per query.
// All GEMMs via v_mfma_f32_16x16x32_f16. LDS 58 KB -> 2 blocks/CU.
// ---------------------------------------------------------------------------
__global__ __launch_bounds__(256, 2)
void fieldformer_mfma(const int* __restrict__ q_lin_idx,
                      const int* __restrict__ offsets_ijk,
                      const float* __restrict__ coords,
                      const float* __restrict__ vals,
                      const float* __restrict__ log_gammas,
                      const float* __restrict__ proj_w,
                      const float* __restrict__ proj_b,
                      const float* __restrict__ qkv_b,
                      const float* __restrict__ out_b,
                      const float* __restrict__ ln1_s,
                      const float* __restrict__ ln1_b,
                      const float* __restrict__ ff1_b,
                      const float* __restrict__ ff2_b,
                      const float* __restrict__ ln2_s,
                      const float* __restrict__ ln2_b,
                      const float* __restrict__ head_ln_s,
                      const float* __restrict__ head_ln_b,
                      const float* __restrict__ head1_w,
                      const float* __restrict__ head1_b,
                      const float* __restrict__ head2_w,
                      const float* __restrict__ head2_b,
                      const _Float16* __restrict__ wH,
                      float* __restrict__ out) {
  // LDS regions. Strides chosen so row stride ≡ 16 B (mod 128 B): b128
  // fragment reads spread uniformly over the 8 bank-granule classes.
  __shared__ __align__(16) _Float16 sX[128 * 72];     // X  (activations, f16)
  __shared__ __align__(16) _Float16 sPH[128 * 136];   // P (per-head) / FF-hidden; Qh/Kh live in its head
  __shared__ __align__(16) _Float16 sVO[3072];        // Vt (16x136) then O_h (128x24)

  _Float16* sQ = sPH;          // [128][24]  (valid QKV-write .. scores-read)
  _Float16* sK = sPH + 3072;   // [128][24]
  _Float16* sV = sVO;          // [16][136]  V^T for this head
  _Float16* sO = sVO;          // [128][24]  O_h after PV

  const int tid = threadIdx.x;
  const int wv = tid >> 6;
  const int lane = tid & 63;
  const int quad = lane >> 4;
  const int l15 = lane & 15;
  const int b = blockIdx.x;

  // ---------------- phase 0: tokens -> proj -> sX (f32 VALU, tiny) --------
  {
    const int row = tid >> 1, hf = tid & 1;
    const int q = q_lin_idx[b];
    const int qi = q / (NYg * NTg);
    const int qrem = q - qi * (NYg * NTg);
    const int qj = qrem / NTg;
    const int qk = qrem - qj * NTg;
    const int di = offsets_ijk[row * 3 + 0];
    const int dj = offsets_ijk[row * 3 + 1];
    const int dk = offsets_ijk[row * 3 + 2];
    const int I = (qi + di) % NXg;
    const int J = (qj + dj) % NYg;
    int T = qk + dk; T = T < 0 ? 0 : (T > NTg - 1 ? NTg - 1 : T);
    const int nb = I * (NYg * NTg) + J * NTg + T;
    const float qx = coords[q * 3 + 0], qy = coords[q * 3 + 1], qz = coords[q * 3 + 2];
    const float nx_ = coords[nb * 3 + 0], ny_ = coords[nb * 3 + 1], nz_ = coords[nb * 3 + 2];
    float ax = nx_ - qx + 1.0f; ax -= 2.0f * floorf(ax * 0.5f); ax -= 1.0f;
    float ay = ny_ - qy + 1.0f; ay -= 2.0f * floorf(ay * 0.5f); ay -= 1.0f;
    const float at = nz_ - qz;
    float tok[6];
    tok[0] = ax * expf(log_gammas[0]);
    tok[1] = ay * expf(log_gammas[1]);
    tok[2] = at * expf(log_gammas[2]);
    tok[3] = vals[nb * 3 + 0];
    tok[4] = vals[nb * 3 + 1];
    tok[5] = vals[nb * 3 + 2];
#pragma unroll
    for (int ci = 0; ci < 32; ++ci) {
      const int c = hf * 32 + ci;
      const float* w = proj_w + c * 6;
      float a = proj_b[c];
      a = fmaf(tok[0], w[0], a); a = fmaf(tok[1], w[1], a);
      a = fmaf(tok[2], w[2], a); a = fmaf(tok[3], w[3], a);
      a = fmaf(tok[4], w[4], a); a = fmaf(tok[5], w[5], a);
      sX[row * 72 + c] = (_Float16)a;
    }
  }
  __syncthreads();

  // ---------------- transformer layers ------------------------------------
  for (int l = 0; l < NLAYER; ++l) {
    const _Float16* qkvH = wH + l * 192 * 64;
    const _Float16* woutH = wH + 24576 + l * 64 * 64;
    const _Float16* ff1H = wH + 32768 + l * 128 * 64;
    const _Float16* ff2H = wH + 49152 + l * 64 * 128;
    const float* bqkv = qkv_b + l * 192;

    // X A-fragments for this layer's attention projections (rows = own m-tiles)
    f16x8 axx[2][2];
#pragma unroll
    for (int mi = 0; mi < 2; ++mi)
#pragma unroll
      for (int kt = 0; kt < 2; ++kt)
        axx[mi][kt] = ld8(sX + ((wv * 2 + mi) * 16 + l15) * 72 + kt * 32 + quad * 8);

    f32x4 y2[2][4];  // attention out-proj accumulator (lives across head loop)
#pragma unroll
    for (int mi = 0; mi < 2; ++mi)
#pragma unroll
      for (int nt = 0; nt < 4; ++nt) y2[mi][nt] = f32x4{0.f, 0.f, 0.f, 0.f};

    for (int h = 0; h < NH; ++h) {
      // ---- phase A: Q_h, K_h, V_h = X @ W^T (M=128,N=16,K=64) ----
      f32x4 dq[2] = {f32x4{0.f,0.f,0.f,0.f}, f32x4{0.f,0.f,0.f,0.f}};
      f32x4 dk[2] = {f32x4{0.f,0.f,0.f,0.f}, f32x4{0.f,0.f,0.f,0.f}};
      f32x4 dv[2] = {f32x4{0.f,0.f,0.f,0.f}, f32x4{0.f,0.f,0.f,0.f}};
#pragma unroll
      for (int kt = 0; kt < 2; ++kt) {
        f16x8 bq = ld8(qkvH + (h * 16 + l15) * 64 + kt * 32 + quad * 8);
        f16x8 bk = ld8(qkvH + (64 + h * 16 + l15) * 64 + kt * 32 + quad * 8);
        f16x8 bv = ld8(qkvH + (128 + h * 16 + l15) * 64 + kt * 32 + quad * 8);
#pragma unroll
        for (int mi = 0; mi < 2; ++mi) {
          dq[mi] = MFMA16(axx[mi][kt], bq, dq[mi]);
          dk[mi] = MFMA16(axx[mi][kt], bk, dk[mi]);
          dv[mi] = MFMA16(axx[mi][kt], bv, dv[mi]);
        }
      }
      {
        const float bq_ = bqkv[h * 16 + l15];
        const float bk_ = bqkv[64 + h * 16 + l15];
        const float bv_ = bqkv[128 + h * 16 + l15];
#pragma unroll
        for (int mi = 0; mi < 2; ++mi)
#pragma unroll
          for (int jr = 0; jr < 4; ++jr) {
            int row = (wv * 2 + mi) * 16 + quad * 4 + jr;
            sQ[row * 24 + l15] = (_Float16)((dq[mi][jr] + bq_) * 0.25f);  // fold 1/sqrt(dh)
            sK[row * 24 + l15] = (_Float16)(dk[mi][jr] + bk_);
            sV[l15 * 136 + row] = (_Float16)(dv[mi][jr] + bv_);           // V^T
          }
      }
      __syncthreads();  // b1: Q/K/V visible to all waves

      // ---- scores: S = Q_h K_h^T (K=16 zero-padded to 32) ----
      f32x4 sc[2][8];
#pragma unroll
      for (int mi = 0; mi < 2; ++mi)
#pragma unroll
        for (int nt = 0; nt < 8; ++nt) sc[mi][nt] = f32x4{0.f, 0.f, 0.f, 0.f};
      f16x8 aq[2];
#pragma unroll
      for (int mi = 0; mi < 2; ++mi) {
        aq[mi] = zero8();
        if (quad < 2) aq[mi] = ld8(sQ + ((wv * 2 + mi) * 16 + l15) * 24 + quad * 8);
      }
#pragma unroll
      for (int nt = 0; nt < 8; ++nt) {
        f16x8 bk = zero8();
        if (quad < 2) bk = ld8(sK + (nt * 16 + l15) * 24 + quad * 8);
#pragma unroll
        for (int mi = 0; mi < 2; ++mi) sc[mi][nt] = MFMA16(aq[mi], bk, sc[mi][nt]);
      }
      __syncthreads();  // b2: all Q/K reads done; P may now overwrite that space

      // ---- softmax in-register (rows live in 16-lane groups), write P ----
#pragma unroll
      for (int mi = 0; mi < 2; ++mi) {
#pragma unroll
        for (int jr = 0; jr < 4; ++jr) {
          float m0 = sc[mi][0][jr];
#pragma unroll
          for (int nt = 1; nt < 8; ++nt) m0 = fmaxf(m0, sc[mi][nt][jr]);
          m0 = fmaxf(m0, __shfl_xor(m0, 1, 64));
          m0 = fmaxf(m0, __shfl_xor(m0, 2, 64));
          m0 = fmaxf(m0, __shfl_xor(m0, 4, 64));
          m0 = fmaxf(m0, __shfl_xor(m0, 8, 64));
          float s0 = 0.f;
#pragma unroll
          for (int nt = 0; nt < 8; ++nt) {
            float e = __expf(sc[mi][nt][jr] - m0);
            sc[mi][nt][jr] = e;
            s0 += e;
          }
          s0 += __shfl_xor(s0, 1, 64);
          s0 += __shfl_xor(s0, 2, 64);
          s0 += __shfl_xor(s0, 4, 64);
          s0 += __shfl_xor(s0, 8, 64);
          const float inv = 1.0f / s0;
          const int row = (wv * 2 + mi) * 16 + quad * 4 + jr;
#pragma unroll
          for (int nt = 0; nt < 8; ++nt)
            sPH[row * 136 + nt * 16 + l15] = (_Float16)(sc[mi][nt][jr] * inv);
        }
      }
      // own rows only are read below -> no barrier needed before PV A-reads

      // ---- PV: O_h = P V_h (M=128,N=16,K=128) ----
      f32x4 ov[2] = {f32x4{0.f,0.f,0.f,0.f}, f32x4{0.f,0.f,0.f,0.f}};
#pragma unroll
      for (int kt = 0; kt < 4; ++kt) {
        f16x8 bv = ld8(sV + l15 * 136 + kt * 32 + quad * 8);
#pragma unroll
        for (int mi = 0; mi < 2; ++mi) {
          f16x8 ap = ld8(sPH + ((wv * 2 + mi) * 16 + l15) * 136 + kt * 32 + quad * 8);
          ov[mi] = MFMA16(ap, bv, ov[mi]);
        }
      }
      __syncthreads();  // b4: P & V reads done; sVO may become O_h
#pragma unroll
      for (int mi = 0; mi < 2; ++mi)
#pragma unroll
        for (int jr = 0; jr < 4; ++jr) {
          int row = (wv * 2 + mi) * 16 + quad * 4 + jr;
          sO[row * 24 + l15] = (_Float16)ov[mi][jr];
        }
      // own rows only read below -> no barrier

      // ---- out-proj partial: Y2 += O_h @ Wout[:, h*16:+16]^T (K=16 pad 32) ----
      f16x8 ao[2];
#pragma unroll
      for (int mi = 0; mi < 2; ++mi) {
        ao[mi] = zero8();
        if (quad < 2) ao[mi] = ld8(sO + ((wv * 2 + mi) * 16 + l15) * 24 + quad * 8);
      }
#pragma unroll
      for (int nt = 0; nt < 4; ++nt) {
        f16x8 bo = zero8();
        if (quad < 2) bo = ld8(woutH + (nt * 16 + l15) * 64 + h * 16 + quad * 8);
#pragma unroll
        for (int mi = 0; mi < 2; ++mi) y2[mi][nt] = MFMA16(ao[mi], bo, y2[mi][nt]);
      }
      __syncthreads();  // b6: O_h reads done; next head may overwrite sQ/sK/sV
    }  // heads

    // ---- attention epilogue: bias + residual + LN1 -> sX ----
    res_ln_store(y2, out_b + l * 64, ln1_s + l * 64, ln1_b + l * 64, sX, wv, quad, l15);
    // all subsequent reads of sX / sPH in FF are own-row -> no barrier

    // ---- FF1: Hh = relu(X @ W1^T + b1) (M=128,N=128,K=64) ----
    f32x4 f[2][8];
#pragma unroll
    for (int mi = 0; mi < 2; ++mi)
#pragma unroll
      for (int nt = 0; nt < 8; ++nt) f[mi][nt] = f32x4{0.f, 0.f, 0.f, 0.f};
#pragma unroll
    for (int kt = 0; kt < 2; ++kt) {
      f16x8 ax2[2];
#pragma unroll
      for (int mi = 0; mi < 2; ++mi)
        ax2[mi] = ld8(sX + ((wv * 2 + mi) * 16 + l15) * 72 + kt * 32 + quad * 8);
#pragma unroll
      for (int nt = 0; nt < 8; ++nt) {
        f16x8 bw = ld8(ff1H + (nt * 16 + l15) * 64 + kt * 32 + quad * 8);
#pragma unroll
        for (int mi = 0; mi < 2; ++mi) f[mi][nt] = MFMA16(ax2[mi], bw, f[mi][nt]);
      }
    }
    {
      const float* b1 = ff1_b + l * 128;
#pragma unroll
      for (int nt = 0; nt < 8; ++nt) {
        const float bb = b1[nt * 16 + l15];
#pragma unroll
        for (int mi = 0; mi < 2; ++mi)
#pragma unroll
          for (int jr = 0; jr < 4; ++jr) {
            int row = (wv * 2 + mi) * 16 + quad * 4 + jr;
            float v = fmaxf(f[mi][nt][jr] + bb, 0.f);
            sPH[row * 136 + nt * 16 + l15] = (_Float16)v;
          }
      }
    }

    // ---- FF2 + residual + LN2 -> sX (M=128,N=64,K=128) ----
    f32x4 g2[2][4];
#pragma unroll
    for (int mi = 0; mi < 2; ++mi)
#pragma unroll
      for (int nt = 0; nt < 4; ++nt) g2[mi][nt] = f32x4{0.f, 0.f, 0.f, 0.f};
#pragma unroll
    for (int kt = 0; kt < 4; ++kt) {
      f16x8 ah[2];
#pragma unroll
      for (int mi = 0; mi < 2; ++mi)
        ah[mi] = ld8(sPH + ((wv * 2 + mi) * 16 + l15) * 136 + kt * 32 + quad * 8);
#pragma unroll
      for (int nt = 0; nt < 4; ++nt) {
        f16x8 bw = ld8(ff2H + (nt * 16 + l15) * 128 + kt * 32 + quad * 8);
#pragma unroll
        for (int mi = 0; mi < 2; ++mi) g2[mi][nt] = MFMA16(ah[mi], bw, g2[mi][nt]);
      }
    }
    res_ln_store(g2, ff2_b + l * 64, ln2_s + l * 64, ln2_b + l * 64, sX, wv, quad, l15);
    __syncthreads();  // end of layer: sPH (H) dead before next layer's Q/K writes
  }  // layers

  // ---------------- head: mean over S, LN, gelu-MLP -> 3 outputs ----------
  {
    float* pf = (float*)sPH;  // 256 partials + 64 gsc + 64 asc
    float* gsc = pf + 256;
    float* asc = pf + 320;
    const int col = tid & 63, rg = tid >> 6;
    float s = 0.f;
    for (int rr = rg * 32; rr < rg * 32 + 32; ++rr) s += (float)sX[rr * 72 + col];
    pf[rg * 64 + col] = s;
    __syncthreads();
    if (tid < 64) {
      const float hm = (pf[tid] + pf[64 + tid] + pf[128 + tid] + pf[192 + tid]) * (1.0f / 128.0f);
      float t = hm;
      t += __shfl_xor(t, 1, 64);  t += __shfl_xor(t, 2, 64);
      t += __shfl_xor(t, 4, 64);  t += __shfl_xor(t, 8, 64);
      t += __shfl_xor(t, 16, 64); t += __shfl_xor(t, 32, 64);
      const float mu = t * (1.0f / 64.0f);
      const float dv = hm - mu;
      float v2 = dv * dv;
      v2 += __shfl_xor(v2, 1, 64);  v2 += __shfl_xor(v2, 2, 64);
      v2 += __shfl_xor(v2, 4, 64);  v2 += __shfl_xor(v2, 8, 64);
      v2 += __shfl_xor(v2, 16, 64); v2 += __shfl_xor(v2, 32, 64);
      const float var = v2 * (1.0f / 64.0f);
      gsc[tid] = fmaf(dv * rsqrtf(var + EPSf), head_ln_s[tid], head_ln_b[tid]);
    }
    __syncthreads();
    if (tid < 64) {
      float z = head1_b[tid];
      for (int k = 0; k < 64; ++k) z = fmaf(gsc[k], head1_w[tid * 64 + k], z);
      asc[tid] = 0.5f * z * (1.0f + erff(z * 0.70710678118654752f));
    }
    __syncthreads();
    if (tid < 3) {
      float z = head2_b[tid];
      for (int k = 0; k < 64; ++k) z = fmaf(asc[k], head2_w[tid * 64 + k], z);
      out[b * 3 + tid] = z;
    }
  }
}

extern "C" void kernel_launch(void* const* d_in, const int* in_sizes, int n_in,
                              void* d_out, int out_size, void* d_ws, size_t ws_size,
                              hipStream_t stream) {
  (void)n_in; (void)ws_size; (void)out_size;
  const int B = in_sizes[0];
  _Float16* wsH = (_Float16*)d_ws;  // 65536 halves = 128 KB

  prep_weights<<<dim3(256), dim3(256), 0, stream>>>(
      (const float*)d_in[7],   // qkv_w
      (const float*)d_in[9],   // out_w
      (const float*)d_in[13],  // ff1_w
      (const float*)d_in[15],  // ff2_w
      wsH);

  fieldformer_mfma<<<dim3(B), dim3(256), 0, stream>>>(
      (const int*)d_in[0],     // q_lin_idx
      (const int*)d_in[1],     // offsets_ijk
      (const float*)d_in[2],   // coords
      (const float*)d_in[3],   // vals
      (const float*)d_in[4],   // log_gammas
      (const float*)d_in[5],   // proj_w
      (const float*)d_in[6],   // proj_b
      (const float*)d_in[8],   // qkv_b
      (const float*)d_in[10],  // out_b
      (const float*)d_in[11],  // ln1_s
      (const float*)d_in[12],  // ln1_b
      (const float*)d_in[14],  // ff1_b
      (const float*)d_in[16],  // ff2_b
      (const float*)d_in[17],  // ln2_s
      (const float*)d_in[18],  // ln2_b
      (const float*)d_in[19],  // head_ln_s
      (const float*)d_in[20],  // head_ln_b
      (const float*)d_in[21],  // head1_w
      (const float*)d_in[22],  // head1_b
      (const float*)d_in[23],  // head2_w
      (const float*)d_in[24],  // head2_b
      wsH,
      (float*)d_out);
}

// Round 4
// 348.871 us; speedup vs baseline: 8.6426x; 1.1911x over previous
//
#include <hip/hip_runtime.h>
#include <math.h>

#define NXg 128
#define NYg 128
#define NTg 64
#define SEQ 128
#define DIM 64
#define NH 4
#define DHd 16
#define DFFd 128
#define NLAYER 2
#define EPSf 1e-5f

typedef _Float16 f16x8 __attribute__((ext_vector_type(8)));
typedef _Float16 f16x4 __attribute__((ext_vector_type(4)));
typedef float f32x4 __attribute__((ext_vector_type(4)));

#define MFMA16(a, b, c) __builtin_amdgcn_mfma_f32_16x16x32_f16(a, b, c, 0, 0, 0)

__device__ __forceinline__ f16x8 zero8() {
  f16x8 z;
#pragma unroll
  for (int i = 0; i < 8; ++i) z[i] = (_Float16)0.0f;
  return z;
}
__device__ __forceinline__ f16x8 ld8(const _Float16* p) { return *(const f16x8*)p; }

// ---------------------------------------------------------------------------
// Prep: convert weight matrices to f16 into workspace.
// ws layout (halves): [0) qkv L*192*64, [24576) out L*64*64,
//                     [32768) ff1 L*128*64, [49152) ff2 L*64*128
// ---------------------------------------------------------------------------
__global__ void prep_weights(const float* __restrict__ qkv_w,
                             const float* __restrict__ out_w,
                             const float* __restrict__ ff1_w,
                             const float* __restrict__ ff2_w,
                             _Float16* __restrict__ wsH) {
  int i = blockIdx.x * 256 + threadIdx.x;
  if (i < 24576) wsH[i] = (_Float16)qkv_w[i];
  else if (i < 32768) wsH[i] = (_Float16)out_w[i - 24576];
  else if (i < 49152) wsH[i] = (_Float16)ff1_w[i - 32768];
  else if (i < 65536) wsH[i] = (_Float16)ff2_w[i - 49152];
}

// residual + LayerNorm on TRANSPOSED accumulators: acc[mt][qt] holds
// Y^T[out = mt*16 + quad*4 + jr][q = (wv*2+qt)*16 + l15].
// LN is over out-dims: 16 in-lane values + cross-quad shfl(16,32).
// Residual/result in sX row-major [q][72] -> b64 reads/writes.
__device__ __forceinline__ void res_ln_T(f32x4 acc[4][2],
                                         const float* __restrict__ bias,
                                         const float* __restrict__ lns,
                                         const float* __restrict__ lnb,
                                         _Float16* sX,
                                         int wv, int quad, int l15) {
  f32x4 bb[4], sv[4], bv[4];
#pragma unroll
  for (int mt = 0; mt < 4; ++mt) {
    bb[mt] = *(const f32x4*)(bias + mt * 16 + quad * 4);
    sv[mt] = *(const f32x4*)(lns + mt * 16 + quad * 4);
    bv[mt] = *(const f32x4*)(lnb + mt * 16 + quad * 4);
  }
#pragma unroll
  for (int qt = 0; qt < 2; ++qt) {
    const int q = (wv * 2 + qt) * 16 + l15;
    float v[4][4];
#pragma unroll
    for (int mt = 0; mt < 4; ++mt) {
      f16x4 rx = *(const f16x4*)(sX + q * 72 + mt * 16 + quad * 4);
#pragma unroll
      for (int jr = 0; jr < 4; ++jr)
        v[mt][jr] = acc[mt][qt][jr] + bb[mt][jr] + (float)rx[jr];
    }
    float s = 0.f;
#pragma unroll
    for (int mt = 0; mt < 4; ++mt)
#pragma unroll
      for (int jr = 0; jr < 4; ++jr) s += v[mt][jr];
    s += __shfl_xor(s, 16, 64);
    s += __shfl_xor(s, 32, 64);
    const float mu = s * (1.0f / 64.0f);
    float q2 = 0.f;
#pragma unroll
    for (int mt = 0; mt < 4; ++mt)
#pragma unroll
      for (int jr = 0; jr < 4; ++jr) { float d = v[mt][jr] - mu; q2 = fmaf(d, d, q2); }
    q2 += __shfl_xor(q2, 16, 64);
    q2 += __shfl_xor(q2, 32, 64);
    const float rstd = rsqrtf(q2 * (1.0f / 64.0f) + EPSf);
#pragma unroll
    for (int mt = 0; mt < 4; ++mt) {
      f16x4 o;
#pragma unroll
      for (int jr = 0; jr < 4; ++jr)
        o[jr] = (_Float16)fmaf((v[mt][jr] - mu) * rstd, sv[mt][jr], bv[mt][jr]);
      *(f16x4*)(sX + q * 72 + mt * 16 + quad * 4) = o;
    }
  }
}

// ---------------------------------------------------------------------------
// Fused FieldFormer block, fully transposed dataflow (queries on N/l15 axis).
// One workgroup (256 thr = 4 waves) per query. LDS ~68 KB -> 2 blocks/CU.
// ---------------------------------------------------------------------------
__global__ __launch_bounds__(256, 2)
void fieldformer_mfma(const int* __restrict__ q_lin_idx,
                      const int* __restrict__ offsets_ijk,
                      const float* __restrict__ coords,
                      const float* __restrict__ vals,
                      const float* __restrict__ log_gammas,
                      const float* __restrict__ proj_w,
                      const float* __restrict__ proj_b,
                      const float* __restrict__ qkv_b,
                      const float* __restrict__ out_b,
                      const float* __restrict__ ln1_s,
                      const float* __restrict__ ln1_b,
                      const float* __restrict__ ff1_b,
                      const float* __restrict__ ff2_b,
                      const float* __restrict__ ln2_s,
                      const float* __restrict__ ln2_b,
                      const float* __restrict__ head_ln_s,
                      const float* __restrict__ head_ln_b,
                      const float* __restrict__ head1_w,
                      const float* __restrict__ head1_b,
                      const float* __restrict__ head2_w,
                      const float* __restrict__ head2_b,
                      const _Float16* __restrict__ wH,
                      float* __restrict__ out) {
  __shared__ __align__(16) _Float16 sX[128 * 72];    // X row-major [tok][72]
  __shared__ __align__(16) _Float16 sPH[128 * 136];  // P / FF-hidden [tok][136]
  __shared__ __align__(16) _Float16 sQ[128 * 24];    // Q [tok][24]; aliased as O
  __shared__ __align__(16) _Float16 sK[128 * 24];    // K [tok][24]
  __shared__ __align__(16) _Float16 sV[16 * 136];    // V^T [dh][136]

  _Float16* sO = sQ;  // O [tok][24]; safe: Q only ever read by own wave (scores B)

  const int tid = threadIdx.x;
  const int wv = tid >> 6;
  const int lane = tid & 63;
  const int quad = lane >> 4;
  const int l15 = lane & 15;
  const int b = blockIdx.x;

  // ---------------- phase 0: tokens -> proj -> sX --------------------------
  {
    const int row = tid >> 1, hf = tid & 1;
    const int q = q_lin_idx[b];
    const int qi = q / (NYg * NTg);
    const int qrem = q - qi * (NYg * NTg);
    const int qj = qrem / NTg;
    const int qk = qrem - qj * NTg;
    const int di = offsets_ijk[row * 3 + 0];
    const int dj = offsets_ijk[row * 3 + 1];
    const int dk = offsets_ijk[row * 3 + 2];
    const int I = (qi + di) % NXg;
    const int J = (qj + dj) % NYg;
    int T = qk + dk; T = T < 0 ? 0 : (T > NTg - 1 ? NTg - 1 : T);
    const int nb = I * (NYg * NTg) + J * NTg + T;
    const float qx = coords[q * 3 + 0], qy = coords[q * 3 + 1], qz = coords[q * 3 + 2];
    const float nx_ = coords[nb * 3 + 0], ny_ = coords[nb * 3 + 1], nz_ = coords[nb * 3 + 2];
    float ax = nx_ - qx + 1.0f; ax -= 2.0f * floorf(ax * 0.5f); ax -= 1.0f;
    float ay = ny_ - qy + 1.0f; ay -= 2.0f * floorf(ay * 0.5f); ay -= 1.0f;
    const float at = nz_ - qz;
    float tok[6];
    tok[0] = ax * expf(log_gammas[0]);
    tok[1] = ay * expf(log_gammas[1]);
    tok[2] = at * expf(log_gammas[2]);
    tok[3] = vals[nb * 3 + 0];
    tok[4] = vals[nb * 3 + 1];
    tok[5] = vals[nb * 3 + 2];
#pragma unroll
    for (int ci = 0; ci < 32; ++ci) {
      const int c = hf * 32 + ci;
      const float* w = proj_w + c * 6;
      float a = proj_b[c];
      a = fmaf(tok[0], w[0], a); a = fmaf(tok[1], w[1], a);
      a = fmaf(tok[2], w[2], a); a = fmaf(tok[3], w[3], a);
      a = fmaf(tok[4], w[4], a); a = fmaf(tok[5], w[5], a);
      sX[row * 72 + c] = (_Float16)a;
    }
  }
  __syncthreads();

  // ---------------- transformer layers ------------------------------------
  for (int l = 0; l < NLAYER; ++l) {
    const _Float16* qkvH = wH + l * 192 * 64;
    const _Float16* woutH = wH + 24576 + l * 64 * 64;
    const _Float16* ff1H = wH + 32768 + l * 128 * 64;
    const _Float16* ff2H = wH + 49152 + l * 64 * 128;
    const float* bqkv = qkv_b + l * 192;

    // X^T B-fragments (per qt, per kt): reused by Q/K/V across all heads
    f16x8 bx[2][2];
#pragma unroll
    for (int qt = 0; qt < 2; ++qt)
#pragma unroll
      for (int kt = 0; kt < 2; ++kt)
        bx[qt][kt] = ld8(sX + ((wv * 2 + qt) * 16 + l15) * 72 + kt * 32 + quad * 8);

    f32x4 y2[4][2];  // Y^T accumulator (out m-tiles x q n-tiles), across heads
#pragma unroll
    for (int mt = 0; mt < 4; ++mt)
#pragma unroll
      for (int qt = 0; qt < 2; ++qt) y2[mt][qt] = f32x4{0.f, 0.f, 0.f, 0.f};

    for (int h = 0; h < NH; ++h) {
      // ---- Q^T/K^T/V^T = W * X^T (M=16 dh, N=queries, K=64) ----
      f32x4 dq[2] = {f32x4{0.f,0.f,0.f,0.f}, f32x4{0.f,0.f,0.f,0.f}};
      f32x4 dk[2] = {f32x4{0.f,0.f,0.f,0.f}, f32x4{0.f,0.f,0.f,0.f}};
      f32x4 dv[2] = {f32x4{0.f,0.f,0.f,0.f}, f32x4{0.f,0.f,0.f,0.f}};
#pragma unroll
      for (int kt = 0; kt < 2; ++kt) {
        f16x8 awq = ld8(qkvH + (h * 16 + l15) * 64 + kt * 32 + quad * 8);
        f16x8 awk = ld8(qkvH + (64 + h * 16 + l15) * 64 + kt * 32 + quad * 8);
        f16x8 awv = ld8(qkvH + (128 + h * 16 + l15) * 64 + kt * 32 + quad * 8);
#pragma unroll
        for (int qt = 0; qt < 2; ++qt) {
          dq[qt] = MFMA16(awq, bx[qt][kt], dq[qt]);
          dk[qt] = MFMA16(awk, bx[qt][kt], dk[qt]);
          dv[qt] = MFMA16(awv, bx[qt][kt], dv[qt]);
        }
      }
      {
        const f32x4 bq4 = *(const f32x4*)(bqkv + h * 16 + quad * 4);
        const f32x4 bk4 = *(const f32x4*)(bqkv + 64 + h * 16 + quad * 4);
        const f32x4 bv4 = *(const f32x4*)(bqkv + 128 + h * 16 + quad * 4);
#pragma unroll
        for (int qt = 0; qt < 2; ++qt) {
          const int q = (wv * 2 + qt) * 16 + l15;
          f16x4 pq, pk;
#pragma unroll
          for (int jr = 0; jr < 4; ++jr) {
            pq[jr] = (_Float16)((dq[qt][jr] + bq4[jr]) * 0.25f);  // fold 1/sqrt(dh)
            pk[jr] = (_Float16)(dk[qt][jr] + bk4[jr]);
            sV[(quad * 4 + jr) * 136 + q] = (_Float16)(dv[qt][jr] + bv4[jr]);
          }
          *(f16x4*)(sQ + q * 24 + quad * 4) = pq;  // b64 packed
          *(f16x4*)(sK + q * 24 + quad * 4) = pk;
        }
      }
      __syncthreads();  // barrier A: Q/K/V visible

      // ---- S^T = K * Q^T (M=keys 8 tiles, N=queries, K=16 pad 32) ----
      f16x8 bq[2];
#pragma unroll
      for (int qt = 0; qt < 2; ++qt)
        bq[qt] = (quad < 2) ? ld8(sQ + ((wv * 2 + qt) * 16 + l15) * 24 + quad * 8)
                            : zero8();
      f32x4 sc[8][2];
#pragma unroll
      for (int mt = 0; mt < 8; ++mt)
#pragma unroll
        for (int qt = 0; qt < 2; ++qt) sc[mt][qt] = f32x4{0.f, 0.f, 0.f, 0.f};
#pragma unroll
      for (int mt = 0; mt < 8; ++mt) {
        f16x8 ak = (quad < 2) ? ld8(sK + (mt * 16 + l15) * 24 + quad * 8) : zero8();
#pragma unroll
        for (int qt = 0; qt < 2; ++qt) sc[mt][qt] = MFMA16(ak, bq[qt], sc[mt][qt]);
      }

      // ---- softmax over keys (in-lane 32 + cross-quad shfl), write P ----
#pragma unroll
      for (int qt = 0; qt < 2; ++qt) {
        const int q = (wv * 2 + qt) * 16 + l15;
        float m0 = sc[0][qt][0];
#pragma unroll
        for (int mt = 0; mt < 8; ++mt)
#pragma unroll
          for (int jr = 0; jr < 4; ++jr) m0 = fmaxf(m0, sc[mt][qt][jr]);
        m0 = fmaxf(m0, __shfl_xor(m0, 16, 64));
        m0 = fmaxf(m0, __shfl_xor(m0, 32, 64));
        float s0 = 0.f;
#pragma unroll
        for (int mt = 0; mt < 8; ++mt)
#pragma unroll
          for (int jr = 0; jr < 4; ++jr) {
            float e = __expf(sc[mt][qt][jr] - m0);
            sc[mt][qt][jr] = e;
            s0 += e;
          }
        s0 += __shfl_xor(s0, 16, 64);
        s0 += __shfl_xor(s0, 32, 64);
        const float inv = 1.0f / s0;
#pragma unroll
        for (int mt = 0; mt < 8; ++mt) {
          f16x4 pp;
#pragma unroll
          for (int jr = 0; jr < 4; ++jr) pp[jr] = (_Float16)(sc[mt][qt][jr] * inv);
          *(f16x4*)(sPH + q * 136 + mt * 16 + quad * 4) = pp;  // own row
        }
      }

      // ---- O^T = V^T * P^T (M=16 dh, N=queries, K=128 keys) ----
      f32x4 ov[2] = {f32x4{0.f,0.f,0.f,0.f}, f32x4{0.f,0.f,0.f,0.f}};
#pragma unroll
      for (int kt = 0; kt < 4; ++kt) {
        f16x8 av = ld8(sV + l15 * 136 + kt * 32 + quad * 8);
#pragma unroll
        for (int qt = 0; qt < 2; ++qt) {
          f16x8 bp = ld8(sPH + ((wv * 2 + qt) * 16 + l15) * 136 + kt * 32 + quad * 8);
          ov[qt] = MFMA16(av, bp, ov[qt]);
        }
      }
      __syncthreads();  // barrier B: all cross-wave reads of sQ/sK/sV done

      // O -> LDS (aliases sQ), own rows, b64 packed
#pragma unroll
      for (int qt = 0; qt < 2; ++qt) {
        const int q = (wv * 2 + qt) * 16 + l15;
        f16x4 po;
#pragma unroll
        for (int jr = 0; jr < 4; ++jr) po[jr] = (_Float16)ov[qt][jr];
        *(f16x4*)(sO + q * 24 + quad * 4) = po;
      }

      // ---- Y^T += Wout_h * O_h^T (M=64 out, N=queries, K=16 pad 32) ----
      f16x8 bo[2];
#pragma unroll
      for (int qt = 0; qt < 2; ++qt)
        bo[qt] = (quad < 2) ? ld8(sO + ((wv * 2 + qt) * 16 + l15) * 24 + quad * 8)
                            : zero8();
#pragma unroll
      for (int mt = 0; mt < 4; ++mt) {
        f16x8 aw = (quad < 2) ? ld8(woutH + (mt * 16 + l15) * 64 + h * 16 + quad * 8)
                              : zero8();
#pragma unroll
        for (int qt = 0; qt < 2; ++qt) y2[mt][qt] = MFMA16(aw, bo[qt], y2[mt][qt]);
      }
    }  // heads

    // ---- attention epilogue: bias + residual + LN1 -> sX (own rows) ----
    res_ln_T(y2, out_b + l * 64, ln1_s + l * 64, ln1_b + l * 64, sX, wv, quad, l15);

    // ---- H^T = W1 * X^T, relu (M=128 ff, N=queries, K=64) ----
    f32x4 f[8][2];
#pragma unroll
    for (int mt = 0; mt < 8; ++mt)
#pragma unroll
      for (int qt = 0; qt < 2; ++qt) f[mt][qt] = f32x4{0.f, 0.f, 0.f, 0.f};
#pragma unroll
    for (int kt = 0; kt < 2; ++kt) {
      f16x8 bxn[2];
#pragma unroll
      for (int qt = 0; qt < 2; ++qt)
        bxn[qt] = ld8(sX + ((wv * 2 + qt) * 16 + l15) * 72 + kt * 32 + quad * 8);
#pragma unroll
      for (int mt = 0; mt < 8; ++mt) {
        f16x8 aw = ld8(ff1H + (mt * 16 + l15) * 64 + kt * 32 + quad * 8);
#pragma unroll
        for (int qt = 0; qt < 2; ++qt) f[mt][qt] = MFMA16(aw, bxn[qt], f[mt][qt]);
      }
    }
    {
      const float* b1 = ff1_b + l * 128;
#pragma unroll
      for (int mt = 0; mt < 8; ++mt) {
        const f32x4 bb = *(const f32x4*)(b1 + mt * 16 + quad * 4);
#pragma unroll
        for (int qt = 0; qt < 2; ++qt) {
          const int q = (wv * 2 + qt) * 16 + l15;
          f16x4 ph;
#pragma unroll
          for (int jr = 0; jr < 4; ++jr)
            ph[jr] = (_Float16)fmaxf(f[mt][qt][jr] + bb[jr], 0.f);
          *(f16x4*)(sPH + q * 136 + mt * 16 + quad * 4) = ph;  // own row
        }
      }
    }

    // ---- O2^T = W2 * H^T (M=64 out, N=queries, K=128) + res + LN2 ----
    f32x4 g[4][2];
#pragma unroll
    for (int mt = 0; mt < 4; ++mt)
#pragma unroll
      for (int qt = 0; qt < 2; ++qt) g[mt][qt] = f32x4{0.f, 0.f, 0.f, 0.f};
#pragma unroll
    for (int kt = 0; kt < 4; ++kt) {
      f16x8 bh[2];
#pragma unroll
      for (int qt = 0; qt < 2; ++qt)
        bh[qt] = ld8(sPH + ((wv * 2 + qt) * 16 + l15) * 136 + kt * 32 + quad * 8);
#pragma unroll
      for (int mt = 0; mt < 4; ++mt) {
        f16x8 aw = ld8(ff2H + (mt * 16 + l15) * 128 + kt * 32 + quad * 8);
#pragma unroll
        for (int qt = 0; qt < 2; ++qt) g[mt][qt] = MFMA16(aw, bh[qt], g[mt][qt]);
      }
    }
    res_ln_T(g, ff2_b + l * 64, ln2_s + l * 64, ln2_b + l * 64, sX, wv, quad, l15);
  }  // layers

  // ---------------- head: mean over S, LN, gelu-MLP -> 3 outputs ----------
  __syncthreads();  // sX all rows needed; sPH free for scratch
  {
    float* pf = (float*)sPH;
    float* gsc = pf + 256;
    float* asc = pf + 320;
    const int col = tid & 63, rg = tid >> 6;
    float s = 0.f;
    for (int rr = rg * 32; rr < rg * 32 + 32; ++rr) s += (float)sX[rr * 72 + col];
    pf[rg * 64 + col] = s;
    __syncthreads();
    if (tid < 64) {
      const float hm = (pf[tid] + pf[64 + tid] + pf[128 + tid] + pf[192 + tid]) * (1.0f / 128.0f);
      float t = hm;
      t += __shfl_xor(t, 1, 64);  t += __shfl_xor(t, 2, 64);
      t += __shfl_xor(t, 4, 64);  t += __shfl_xor(t, 8, 64);
      t += __shfl_xor(t, 16, 64); t += __shfl_xor(t, 32, 64);
      const float mu = t * (1.0f / 64.0f);
      const float dv = hm - mu;
      float v2 = dv * dv;
      v2 += __shfl_xor(v2, 1, 64);  v2 += __shfl_xor(v2, 2, 64);
      v2 += __shfl_xor(v2, 4, 64);  v2 += __shfl_xor(v2, 8, 64);
      v2 += __shfl_xor(v2, 16, 64); v2 += __shfl_xor(v2, 32, 64);
      const float var = v2 * (1.0f / 64.0f);
      gsc[tid] = fmaf(dv * rsqrtf(var + EPSf), head_ln_s[tid], head_ln_b[tid]);
    }
    __syncthreads();
    if (tid < 64) {
      float z = head1_b[tid];
      for (int k = 0; k < 64; ++k) z = fmaf(gsc[k], head1_w[tid * 64 + k], z);
      asc[tid] = 0.5f * z * (1.0f + erff(z * 0.70710678118654752f));
    }
    __syncthreads();
    if (tid < 3) {
      float z = head2_b[tid];
      for (int k = 0; k < 64; ++k) z = fmaf(asc[k], head2_w[tid * 64 + k], z);
      out[b * 3 + tid] = z;
    }
  }
}

extern "C" void kernel_launch(void* const* d_in, const int* in_sizes, int n_in,
                              void* d_out, int out_size, void* d_ws, size_t ws_size,
                              hipStream_t stream) {
  (void)n_in; (void)ws_size; (void)out_size;
  const int B = in_sizes[0];
  _Float16* wsH = (_Float16*)d_ws;  // 65536 halves = 128 KB

  prep_weights<<<dim3(256), dim3(256), 0, stream>>>(
      (const float*)d_in[7],   // qkv_w
      (const float*)d_in[9],   // out_w
      (const float*)d_in[13],  // ff1_w
      (const float*)d_in[15],  // ff2_w
      wsH);

  fieldformer_mfma<<<dim3(B), dim3(256), 0, stream>>>(
      (const int*)d_in[0],     // q_lin_idx
      (const int*)d_in[1],     // offsets_ijk
      (const float*)d_in[2],   // coords
      (const float*)d_in[3],   // vals
      (const float*)d_in[4],   // log_gammas
      (const float*)d_in[5],   // proj_w
      (const float*)d_in[6],   // proj_b
      (const float*)d_in[8],   // qkv_b
      (const float*)d_in[10],  // out_b
      (const float*)d_in[11],  // ln1_s
      (const float*)d_in[12],  // ln1_b
      (const float*)d_in[14],  // ff1_b
      (const float*)d_in[16],  // ff2_b
      (const float*)d_in[17],  // ln2_s
      (const float*)d_in[18],  // ln2_b
      (const float*)d_in[19],  // head_ln_s
      (const float*)d_in[20],  // head_ln_b
      (const float*)d_in[21],  // head1_w
      (const float*)d_in[22],  // head1_b
      (const float*)d_in[23],  // head2_w
      (const float*)d_in[24],  // head2_b
      wsH,
      (float*)d_out);
}